// Round 1
// baseline (495.189 us; speedup 1.0000x reference)
//
#include <hip/hip_runtime.h>
#include <math.h>

#define C_DIM 128
#define S_DIM 1024
#define B_TOT 64

// ---------------------------------------------------------------------------
// K0: transpose W (32,128) -> Wt (128,32) so the proj kernel can read W with
// uniform (scalar) loads of 32 consecutive floats per channel.
// ---------------------------------------------------------------------------
__global__ __launch_bounds__(256) void k_wt(const float* __restrict__ Ww,
                                            float* __restrict__ Wt) {
    for (int e = threadIdx.x; e < 32 * C_DIM; e += 256) {
        int d = e >> 7, c = e & (C_DIM - 1);
        Wt[c * 32 + d] = Ww[e];
    }
}

// ---------------------------------------------------------------------------
// K1: per token: q = l2norm(W(x1+p1)+b)*30 ; k = l2norm(W(x2+p2)+b)
//     x reads are stride-S (coalesced across the 64 consecutive tokens of a
//     wave); W/bias/pos are loop-uniform -> scalar loads. No LDS.
// ---------------------------------------------------------------------------
__global__ __launch_bounds__(256) void k_proj(
    const float* __restrict__ f1, const float* __restrict__ f2,
    const float* __restrict__ pos1, const float* __restrict__ pos2,
    const float* __restrict__ Wt, const float* __restrict__ Wb,
    float* __restrict__ fq, float* __restrict__ fk) {
    const int g = blockIdx.x * 256 + threadIdx.x;   // token id 0..65535
    const int b = g >> 10;
    const int t = g & (S_DIM - 1);
    const float* x1 = f1 + (size_t)b * C_DIM * S_DIM + t;
    const float* x2 = f2 + (size_t)b * C_DIM * S_DIM + t;
    float q[32], k[32];
#pragma unroll
    for (int d = 0; d < 32; ++d) { q[d] = 0.f; k[d] = 0.f; }
#pragma unroll 4
    for (int c = 0; c < C_DIM; ++c) {
        float a1 = x1[(size_t)c * S_DIM] + pos1[c];
        float a2 = x2[(size_t)c * S_DIM] + pos2[c];
#pragma unroll
        for (int d = 0; d < 32; ++d) {
            float w = Wt[c * 32 + d];
            q[d] = fmaf(w, a1, q[d]);
            k[d] = fmaf(w, a2, k[d]);
        }
    }
    float sq = 0.f, sk = 0.f;
#pragma unroll
    for (int d = 0; d < 32; ++d) {
        q[d] += Wb[d]; k[d] += Wb[d];
        sq = fmaf(q[d], q[d], sq);
        sk = fmaf(k[d], k[d], sk);
    }
    const float rq = 30.0f / fmaxf(sqrtf(sq), 1e-12f);  // fold TEMP into q
    const float rk = 1.0f / fmaxf(sqrtf(sk), 1e-12f);
    float* oq = fq + (size_t)g * 32;
    float* ok = fk + (size_t)g * 32;
#pragma unroll
    for (int c4 = 0; c4 < 8; ++c4) {
        float4 vq = make_float4(q[c4 * 4] * rq, q[c4 * 4 + 1] * rq,
                                q[c4 * 4 + 2] * rq, q[c4 * 4 + 3] * rq);
        float4 vk = make_float4(k[c4 * 4] * rk, k[c4 * 4 + 1] * rk,
                                k[c4 * 4 + 2] * rk, k[c4 * 4 + 3] * rk);
        *(float4*)(oq + c4 * 4) = vq;
        *(float4*)(ok + c4 * 4) = vk;
    }
}

// ---------------------------------------------------------------------------
// K2: flash attention, one block = (batch b, 64-token Q block).
//   thread: rg=tid>>4 -> rows 4rg..4rg+3 ; cg=tid&15
//   QK: 4 rows x 4 kk (kk = 4cg+u), b128 reads from transposed Qt/Kt tiles.
//   PV: 4 rows x 8 c   (c = cg*4..+3 and 64+cg*4..+3), b128 V/P reads.
//   V tile read straight from f_list2 (+pos2): L2-resident (512KB/batch).
//   LDS 59.9KB/block (Kt unioned under Pt) -> 2 blocks/CU.
// ---------------------------------------------------------------------------
__global__ __launch_bounds__(256) void k_attn(
    const float* __restrict__ fq, const float* __restrict__ fk,
    const float* __restrict__ f2, const float* __restrict__ pos2,
    float* __restrict__ fr) {
    __shared__ float Qt[32][64];                       //  8 KB
    __shared__ __align__(16) char KtPt[64 * 68 * 4];   // 17 KB (Kt[32][64] | Pt[64][68])
    __shared__ float Vs[64][132];                      // 33 KB
    __shared__ float p2s[C_DIM];
    float (*Kt)[64] = (float(*)[64])KtPt;
    float (*Pt)[68] = (float(*)[68])KtPt;

    const int tid = threadIdx.x;
    const int qb = blockIdx.x;   // 0..15
    const int b = blockIdx.y;    // 0..63
    const int q0 = qb * 64;
    const int rg = tid >> 4;     // 0..15
    const int cg = tid & 15;     // 0..15

    if (tid < C_DIM) p2s[tid] = pos2[tid];

    // load Q tile transposed: Qt[d][i] = fq[(b*S + q0 + i)*32 + d]
    {
        const float4* src = (const float4*)(fq + ((size_t)b * S_DIM + q0) * 32);
#pragma unroll
        for (int it = 0; it < 2; ++it) {
            int e4 = it * 256 + tid;
            int i = e4 >> 3, d0 = (e4 & 7) << 2;
            float4 v = src[e4];
            Qt[d0 + 0][i] = v.x; Qt[d0 + 1][i] = v.y;
            Qt[d0 + 2][i] = v.z; Qt[d0 + 3][i] = v.w;
        }
    }

    float O[4][8];
    float m[4], l[4];
#pragma unroll
    for (int s = 0; s < 4; ++s) {
        m[s] = -1e30f; l[s] = 0.f;
#pragma unroll
        for (int j = 0; j < 8; ++j) O[s][j] = 0.f;
    }

    for (int kb = 0; kb < 16; ++kb) {
        const int k0 = kb * 64;
        __syncthreads();  // previous iteration's Pt/Vs/Kt consumers done
        // K tile transposed: Kt[d][i] = fk[(b*S + k0 + i)*32 + d]
        {
            const float4* src = (const float4*)(fk + ((size_t)b * S_DIM + k0) * 32);
#pragma unroll
            for (int it = 0; it < 2; ++it) {
                int e4 = it * 256 + tid;
                int i = e4 >> 3, d0 = (e4 & 7) << 2;
                float4 v = src[e4];
                Kt[d0 + 0][i] = v.x; Kt[d0 + 1][i] = v.y;
                Kt[d0 + 2][i] = v.z; Kt[d0 + 3][i] = v.w;
            }
        }
        // V tile: Vs[i][c] = f2[(b*C + c)*S + k0 + i] + pos2[c]
#pragma unroll 8
        for (int it = 0; it < 32; ++it) {
            int e = it * 256 + tid;
            int c = e >> 6, i = e & 63;
            Vs[i][c] = f2[((size_t)b * C_DIM + c) * S_DIM + k0 + i] + p2s[c];
        }
        __syncthreads();  // tiles visible

        // QK: P4[s][u] = q(4rg+s) . k(4cg+u)   (TEMP folded into q)
        float P4[4][4];
#pragma unroll
        for (int s = 0; s < 4; ++s)
#pragma unroll
            for (int u = 0; u < 4; ++u) P4[s][u] = 0.f;
#pragma unroll 8
        for (int d = 0; d < 32; ++d) {
            float qv[4], kv[4];
            *(float4*)qv = *(const float4*)&Qt[d][rg * 4];
            *(float4*)kv = *(const float4*)&Kt[d][cg * 4];
#pragma unroll
            for (int s = 0; s < 4; ++s)
#pragma unroll
                for (int u = 0; u < 4; ++u)
                    P4[s][u] = fmaf(qv[s], kv[u], P4[s][u]);
        }

        // online softmax (row groups = 16 consecutive lanes, shfl width 16)
#pragma unroll
        for (int s = 0; s < 4; ++s) {
            float mx = fmaxf(fmaxf(P4[s][0], P4[s][1]), fmaxf(P4[s][2], P4[s][3]));
            mx = fmaxf(mx, __shfl_xor(mx, 1, 16));
            mx = fmaxf(mx, __shfl_xor(mx, 2, 16));
            mx = fmaxf(mx, __shfl_xor(mx, 4, 16));
            mx = fmaxf(mx, __shfl_xor(mx, 8, 16));
            float mn = fmaxf(m[s], mx);
            float corr = __expf(m[s] - mn);
            float sum = 0.f;
#pragma unroll
            for (int u = 0; u < 4; ++u) {
                P4[s][u] = __expf(P4[s][u] - mn);
                sum += P4[s][u];
            }
            sum += __shfl_xor(sum, 1, 16);
            sum += __shfl_xor(sum, 2, 16);
            sum += __shfl_xor(sum, 4, 16);
            sum += __shfl_xor(sum, 8, 16);
            l[s] = l[s] * corr + sum;
            m[s] = mn;
#pragma unroll
            for (int j = 0; j < 8; ++j) O[s][j] *= corr;
        }
        __syncthreads();  // all QK reads of Kt done (Pt aliases Kt)

        // Pt[kk][r] = P
#pragma unroll
        for (int u = 0; u < 4; ++u) {
            float4 w = make_float4(P4[0][u], P4[1][u], P4[2][u], P4[3][u]);
            *(float4*)&Pt[cg * 4 + u][rg * 4] = w;
        }
        __syncthreads();  // Pt visible

        // PV: O[s][j] += P[4rg+s][kk] * V[kk][c]
#pragma unroll 4
        for (int kk = 0; kk < 64; ++kk) {
            float pv[4], va[8];
            *(float4*)pv = *(const float4*)&Pt[kk][rg * 4];
            *(float4*)va = *(const float4*)&Vs[kk][cg * 4];
            *(float4*)(va + 4) = *(const float4*)&Vs[kk][64 + cg * 4];
#pragma unroll
            for (int s = 0; s < 4; ++s)
#pragma unroll
                for (int j = 0; j < 8; ++j)
                    O[s][j] = fmaf(pv[s], va[j], O[s][j]);
        }
    }

    // residual: reload own token block's V (= f_l2 rows q0..q0+63)
    __syncthreads();
#pragma unroll 8
    for (int it = 0; it < 32; ++it) {
        int e = it * 256 + tid;
        int c = e >> 6, i = e & 63;
        Vs[i][c] = f2[((size_t)b * C_DIM + c) * S_DIM + q0 + i] + p2s[c];
    }
    __syncthreads();

#pragma unroll
    for (int s = 0; s < 4; ++s) {
        const float inv = 1.0f / l[s];
        const int r = rg * 4 + s;
        float va[8], oa[8];
        *(float4*)va = *(const float4*)&Vs[r][cg * 4];
        *(float4*)(va + 4) = *(const float4*)&Vs[r][64 + cg * 4];
#pragma unroll
        for (int j = 0; j < 8; ++j) oa[j] = O[s][j] * inv + va[j];
        float* dst = fr + ((size_t)b * S_DIM + q0 + r) * C_DIM;
        *(float4*)(dst + cg * 4) = *(float4*)oa;
        *(float4*)(dst + 64 + cg * 4) = *(float4*)(oa + 4);
    }
}

// ---------------------------------------------------------------------------
// K3a: per-sample sum of squares (32 blocks per sample, atomic combine)
// ---------------------------------------------------------------------------
__global__ __launch_bounds__(256) void k_ssq(const float* __restrict__ fr,
                                             float* __restrict__ ssq) {
    const int tid = threadIdx.x;
    const float4* p = (const float4*)(fr + (size_t)blockIdx.x * 4096);
    float s = 0.f;
#pragma unroll
    for (int it = 0; it < 4; ++it) {
        float4 v = p[it * 256 + tid];
        s = fmaf(v.x, v.x, fmaf(v.y, v.y, fmaf(v.z, v.z, fmaf(v.w, v.w, s))));
    }
#pragma unroll
    for (int off = 32; off; off >>= 1) s += __shfl_down(s, off, 64);
    __shared__ float wsum[4];
    if ((tid & 63) == 0) wsum[tid >> 6] = s;
    __syncthreads();
    if (tid == 0)
        atomicAdd(&ssq[blockIdx.x >> 5], wsum[0] + wsum[1] + wsum[2] + wsum[3]);
}

// ---------------------------------------------------------------------------
// K3b: out[b][c][t] = fr[b][t][c] * NORM_SCALE*sqrt(CHW/(ssq+1e-5))
//      via 64x128 LDS tile transpose (row pad 133 -> conflict-free col reads)
// ---------------------------------------------------------------------------
__global__ __launch_bounds__(256) void k_out(const float* __restrict__ fr,
                                             const float* __restrict__ ssq,
                                             float* __restrict__ out) {
    __shared__ float Ts[64][133];
    const int tid = threadIdx.x;
    const int b = blockIdx.y, t0 = blockIdx.x * 64;
    const float4* src = (const float4*)(fr + ((size_t)b * S_DIM + t0) * C_DIM);
#pragma unroll
    for (int it = 0; it < 8; ++it) {
        int e4 = it * 256 + tid;
        int t = e4 >> 5, c0 = (e4 & 31) << 2;
        float4 v = src[e4];
        Ts[t][c0] = v.x; Ts[t][c0 + 1] = v.y;
        Ts[t][c0 + 2] = v.z; Ts[t][c0 + 3] = v.w;
    }
    const float scale =
        0.022097086912079608f * sqrtf(131072.0f / (ssq[b] + 1e-5f));
    __syncthreads();
    const int lane = tid & 63, w = tid >> 6;
#pragma unroll
    for (int pass = 0; pass < 32; ++pass) {
        int c = w * 32 + pass;
        out[((size_t)b * C_DIM + c) * S_DIM + t0 + lane] = Ts[lane][c] * scale;
    }
}

// ---------------------------------------------------------------------------
extern "C" void kernel_launch(void* const* d_in, const int* in_sizes, int n_in,
                              void* d_out, int out_size, void* d_ws,
                              size_t ws_size, hipStream_t stream) {
    const float* f1 = (const float*)d_in[0];
    const float* f2 = (const float*)d_in[1];
    const float* pos1 = (const float*)d_in[2];
    const float* pos2 = (const float*)d_in[3];
    const float* Ww = (const float*)d_in[4];
    const float* Wb = (const float*)d_in[5];
    float* out = (float*)d_out;

    // d_out doubles as staging for fq/fk (overwritten by k_out at the end)
    float* fq = out;                       // 64*1024*32 floats
    float* fk = out + 2097152;             // 64*1024*32 floats
    // workspace: fr (33.5MB f32) | ssq (64 f32) | Wt (4096 f32)
    float* fr = (float*)d_ws;
    float* ssq = (float*)((char*)d_ws + 33554432);
    float* Wt = (float*)((char*)d_ws + 33555456);

    k_wt<<<1, 256, 0, stream>>>(Ww, Wt);
    k_proj<<<256, 256, 0, stream>>>(f1, f2, pos1, pos2, Wt, Wb, fq, fk);
    k_attn<<<dim3(16, 64), 256, 0, stream>>>(fq, fk, f2, pos2, fr);
    hipMemsetAsync(ssq, 0, 256, stream);
    k_ssq<<<2048, 256, 0, stream>>>(fr, ssq);
    k_out<<<dim3(16, 64), 256, 0, stream>>>(fr, ssq, out);
}

// Round 3
// 225.355 us; speedup vs baseline: 2.1974x; 2.1974x over previous
//
#include <hip/hip_runtime.h>
#include <math.h>

typedef short s16x8 __attribute__((ext_vector_type(8)));
typedef float f32x4 __attribute__((ext_vector_type(4)));
typedef __bf16 bf16_t;
typedef bf16_t bf16x8 __attribute__((ext_vector_type(8)));
typedef bf16_t bf16x4 __attribute__((ext_vector_type(4)));

#define MFMA16 __builtin_amdgcn_mfma_f32_16x16x32_bf16
#define C_DIM 128
#define S_DIM 1024

// ---------------------------------------------------------------------------
// K0: transpose W (32,128) -> Wt (128,32)
// ---------------------------------------------------------------------------
__global__ __launch_bounds__(256) void k_wt(const float* __restrict__ Ww,
                                            float* __restrict__ Wt) {
    for (int e = threadIdx.x; e < 32 * C_DIM; e += 256) {
        int d = e >> 7, c = e & (C_DIM - 1);
        Wt[c * 32 + d] = Ww[e];
    }
}

// ---------------------------------------------------------------------------
// K_v: Vtb[b][c][t] = bf16(f2[b][c][t] + pos2[c])   (channel-major, final V)
// ---------------------------------------------------------------------------
__global__ __launch_bounds__(256) void k_v(const float* __restrict__ f2,
                                           const float* __restrict__ pos2,
                                           bf16_t* __restrict__ Vtb) {
    const int i = blockIdx.x * 256 + threadIdx.x;        // float4 index
    float4 v = ((const float4*)f2)[i];
    const float p = pos2[(i >> 8) & (C_DIM - 1)];
    bf16x4 o = {(bf16_t)(v.x + p), (bf16_t)(v.y + p),
                (bf16_t)(v.z + p), (bf16_t)(v.w + p)};
    *(bf16x4*)(Vtb + (size_t)i * 4) = o;
}

// ---------------------------------------------------------------------------
// K1: per token: q = l2norm(W(x1+p1)+b)*30 ; k = l2norm(W(x2+p2)+b)  -> bf16
// ---------------------------------------------------------------------------
__global__ __launch_bounds__(256) void k_proj(
    const float* __restrict__ f1, const float* __restrict__ f2,
    const float* __restrict__ pos1, const float* __restrict__ pos2,
    const float* __restrict__ Wt, const float* __restrict__ Wb,
    bf16_t* __restrict__ fqb, bf16_t* __restrict__ fkb) {
    const int g = blockIdx.x * 256 + threadIdx.x;   // token id 0..65535
    const int b = g >> 10;
    const int t = g & (S_DIM - 1);
    const float* x1 = f1 + (size_t)b * C_DIM * S_DIM + t;
    const float* x2 = f2 + (size_t)b * C_DIM * S_DIM + t;
    float q[32], k[32];
#pragma unroll
    for (int d = 0; d < 32; ++d) { q[d] = 0.f; k[d] = 0.f; }
#pragma unroll 4
    for (int c = 0; c < C_DIM; ++c) {
        float a1 = x1[(size_t)c * S_DIM] + pos1[c];
        float a2 = x2[(size_t)c * S_DIM] + pos2[c];
#pragma unroll
        for (int d = 0; d < 32; ++d) {
            float w = Wt[c * 32 + d];
            q[d] = fmaf(w, a1, q[d]);
            k[d] = fmaf(w, a2, k[d]);
        }
    }
    float sq = 0.f, sk = 0.f;
#pragma unroll
    for (int d = 0; d < 32; ++d) {
        q[d] += Wb[d]; k[d] += Wb[d];
        sq = fmaf(q[d], q[d], sq);
        sk = fmaf(k[d], k[d], sk);
    }
    const float rq = 30.0f / fmaxf(sqrtf(sq), 1e-12f);  // fold TEMP into q
    const float rk = 1.0f / fmaxf(sqrtf(sk), 1e-12f);
    bf16_t* oq = fqb + (size_t)g * 32;
    bf16_t* ok = fkb + (size_t)g * 32;
#pragma unroll
    for (int c8 = 0; c8 < 4; ++c8) {
        bf16x8 vq, vk;
#pragma unroll
        for (int j = 0; j < 8; ++j) {
            vq[j] = (bf16_t)(q[c8 * 8 + j] * rq);
            vk[j] = (bf16_t)(k[c8 * 8 + j] * rk);
        }
        *(bf16x8*)(oq + c8 * 8) = vq;
        *(bf16x8*)(ok + c8 * 8) = vk;
    }
}

// ---------------------------------------------------------------------------
// K2: MFMA flash attention. Block = (128 q-rows, batch b), 8 waves x 16 rows.
//   QK:  D[q][key] = mfma(A=Q 16x32, B=K^T)      (4 mfma / wave / 64-key tile)
//   PV (swapped): D[c][q] = mfma(A=V^T 16x32key, B=P^T)  -> channel-major out
//   C/D map (m89): col=lane&15, row=(lane>>4)*4+reg. A row / B col = lane&15.
//   k-index mapping is applied identically to both operands -> permutation-safe.
//   LDS: Ks[64][40] bf16 (pad 8 -> 16B-aligned, spread banks), Vs[128][72],
//        Ps (wave-private P tile) [8][16][72]. 42KB -> 2-3 blocks/CU.
//   fr written channel-major == final layout; per-sample ssq via atomicAdd.
// ---------------------------------------------------------------------------
__global__ __launch_bounds__(512) void k_attn(
    const bf16_t* __restrict__ fqb, const bf16_t* __restrict__ fkb,
    const bf16_t* __restrict__ Vtb, float* __restrict__ fr,
    float* __restrict__ ssq) {
    __shared__ __align__(16) bf16_t Ks[64][40];
    __shared__ __align__(16) bf16_t Vs[128][72];
    __shared__ __align__(16) bf16_t Ps[8][16][72];
    __shared__ float wred[8];

    const int tid = threadIdx.x;
    const int w = tid >> 6;          // wave 0..7
    const int lane = tid & 63;
    const int l15 = lane & 15;
    const int Q = lane >> 4;         // quarter 0..3
    const int b = blockIdx.y;
    const int qw = blockIdx.x * 128 + w * 16;   // wave's first q row

    // Q A-fragment: row=l15 (token qw+l15), k=(Q*8..Q*8+7)
    const s16x8 qa =
        *(const s16x8*)(fqb + ((size_t)b * S_DIM + qw + l15) * 32 + Q * 8);

    f32x4 acc[8];
    const f32x4 fz = {0.f, 0.f, 0.f, 0.f};
#pragma unroll
    for (int cg = 0; cg < 8; ++cg) acc[cg] = fz;
    float m[4] = {-1e30f, -1e30f, -1e30f, -1e30f};
    float lsum[4] = {0.f, 0.f, 0.f, 0.f};

    for (int kb = 0; kb < 16; ++kb) {
        const int k0 = kb * 64;
        __syncthreads();
        // stage K tile: Ks[key][d]
        if (tid < 256) {
            int row = tid >> 2, c8 = (tid & 3) * 8;
            *(s16x8*)&Ks[row][c8] =
                *(const s16x8*)(fkb + ((size_t)b * S_DIM + k0 + row) * 32 + c8);
        }
        // stage V tile: Vs[chan][key]
#pragma unroll
        for (int it = 0; it < 2; ++it) {
            int e = it * 512 + tid;
            int row = e >> 3, c8 = (e & 7) * 8;
            *(s16x8*)&Vs[row][c8] =
                *(const s16x8*)(Vtb + ((size_t)b * C_DIM + row) * S_DIM + k0 + c8);
        }
        __syncthreads();

        // QK^T: sc[n] covers keys 16n..16n+15 for rows qw..qw+15
        f32x4 sc[4];
#pragma unroll
        for (int n = 0; n < 4; ++n) {
            s16x8 kf = *(const s16x8*)&Ks[l15 + 16 * n][Q * 8];
            sc[n] = MFMA16(qa, kf, fz, 0, 0, 0);
        }

        // online softmax; row r = 4*Q+s lives in the 16 lanes of quarter Q
        float corr[4];
#pragma unroll
        for (int s = 0; s < 4; ++s) {
            float mx = fmaxf(fmaxf(sc[0][s], sc[1][s]), fmaxf(sc[2][s], sc[3][s]));
            mx = fmaxf(mx, __shfl_xor(mx, 1, 16));
            mx = fmaxf(mx, __shfl_xor(mx, 2, 16));
            mx = fmaxf(mx, __shfl_xor(mx, 4, 16));
            mx = fmaxf(mx, __shfl_xor(mx, 8, 16));
            float mn = fmaxf(m[s], mx);
            corr[s] = __expf(m[s] - mn);
            float sum = 0.f;
#pragma unroll
            for (int n = 0; n < 4; ++n) {
                float p = __expf(sc[n][s] - mn);
                sum += p;
                Ps[w][4 * Q + s][l15 + 16 * n] = (bf16_t)p;  // wave-private
            }
            sum += __shfl_xor(sum, 1, 16);
            sum += __shfl_xor(sum, 2, 16);
            sum += __shfl_xor(sum, 4, 16);
            sum += __shfl_xor(sum, 8, 16);
            lsum[s] = lsum[s] * corr[s] + sum;
            m[s] = mn;
        }
        // redistribute corr to q-column layout (acc cols = q = l15)
        {
            const int src = (l15 >> 2) << 4;   // a lane of the quarter owning row l15
            float t0 = __shfl(corr[0], src);
            float t1 = __shfl(corr[1], src);
            float t2 = __shfl(corr[2], src);
            float t3 = __shfl(corr[3], src);
            const int rs = l15 & 3;
            const float cq = rs == 0 ? t0 : rs == 1 ? t1 : rs == 2 ? t2 : t3;
#pragma unroll
            for (int cg = 0; cg < 8; ++cg) {
                acc[cg][0] *= cq; acc[cg][1] *= cq;
                acc[cg][2] *= cq; acc[cg][3] *= cq;
            }
        }

        // PV (swapped): acc[cg] holds chans 16cg+4Q+reg, col q = l15
#pragma unroll
        for (int h = 0; h < 2; ++h) {
            s16x8 pb = *(const s16x8*)&Ps[w][l15][h * 32 + Q * 8];
#pragma unroll
            for (int cg = 0; cg < 8; ++cg) {
                s16x8 va = *(const s16x8*)&Vs[16 * cg + l15][h * 32 + Q * 8];
                acc[cg] = MFMA16(va, pb, acc[cg], 0, 0, 0);
            }
        }
    }

    // 1/l redistributed to q-columns
    float invq;
    {
        const int src = (l15 >> 2) << 4;
        float t0 = __shfl(lsum[0], src);
        float t1 = __shfl(lsum[1], src);
        float t2 = __shfl(lsum[2], src);
        float t3 = __shfl(lsum[3], src);
        const int rs = l15 & 3;
        invq = 1.0f / (rs == 0 ? t0 : rs == 1 ? t1 : rs == 2 ? t2 : t3);
    }

    // epilogue: O/l + residual (Vtb), write channel-major fr, accumulate ssq
    float sp = 0.f;
#pragma unroll
    for (int cg = 0; cg < 8; ++cg) {
#pragma unroll
        for (int s = 0; s < 4; ++s) {
            const int c = 16 * cg + 4 * Q + s;
            const size_t idx = ((size_t)b * C_DIM + c) * S_DIM + qw + l15;
            float val = acc[cg][s] * invq + (float)Vtb[idx];
            fr[idx] = val;
            sp = fmaf(val, val, sp);
        }
    }
    sp += __shfl_down(sp, 32);
    sp += __shfl_down(sp, 16);
    sp += __shfl_down(sp, 8);
    sp += __shfl_down(sp, 4);
    sp += __shfl_down(sp, 2);
    sp += __shfl_down(sp, 1);
    if (lane == 0) wred[w] = sp;
    __syncthreads();
    if (tid == 0) {
        float s = 0.f;
#pragma unroll
        for (int i = 0; i < 8; ++i) s += wred[i];
        atomicAdd(&ssq[b], s);
    }
}

// ---------------------------------------------------------------------------
// K3: in-place instance-norm scale of d_out (fr already channel-major)
// ---------------------------------------------------------------------------
__global__ __launch_bounds__(256) void k_out(float* __restrict__ fr,
                                             const float* __restrict__ ssq) {
    const int b = blockIdx.x >> 5;   // 32 blocks of 4096 floats per batch
    const float scale =
        0.022097086912079608f * sqrtf(131072.0f / (ssq[b] + 1e-5f));
    float4* p = (float4*)fr + (size_t)blockIdx.x * 1024;
#pragma unroll
    for (int it = 0; it < 4; ++it) {
        float4 v = p[it * 256 + threadIdx.x];
        v.x *= scale; v.y *= scale; v.z *= scale; v.w *= scale;
        p[it * 256 + threadIdx.x] = v;
    }
}

// ---------------------------------------------------------------------------
extern "C" void kernel_launch(void* const* d_in, const int* in_sizes, int n_in,
                              void* d_out, int out_size, void* d_ws,
                              size_t ws_size, hipStream_t stream) {
    const float* f1 = (const float*)d_in[0];
    const float* f2 = (const float*)d_in[1];
    const float* pos1 = (const float*)d_in[2];
    const float* pos2 = (const float*)d_in[3];
    const float* Ww = (const float*)d_in[4];
    const float* Wb = (const float*)d_in[5];
    float* out = (float*)d_out;

    // ws layout (25.2 MB): fqb | fkb | Vtb | Wt | ssq
    bf16_t* fqb = (bf16_t*)d_ws;
    bf16_t* fkb = fqb + 2097152;
    bf16_t* Vtb = fkb + 2097152;                       // 8,388,608 bf16
    float* Wt = (float*)((char*)d_ws + 25165824);
    float* ssq = (float*)((char*)d_ws + 25182208);

    k_wt<<<1, 256, 0, stream>>>(Ww, Wt);
    k_v<<<8192, 256, 0, stream>>>(f2, pos2, Vtb);
    k_proj<<<256, 256, 0, stream>>>(f1, f2, pos1, pos2, Wt, Wb, fqb, fkb);
    hipMemsetAsync(ssq, 0, 256, stream);
    k_attn<<<dim3(8, 64), 512, 0, stream>>>(fqb, fkb, Vtb, out, ssq);
    k_out<<<2048, 256, 0, stream>>>(out, ssq);
}

// Round 5
// 221.128 us; speedup vs baseline: 2.2394x; 1.0191x over previous
//
#include <hip/hip_runtime.h>
#include <math.h>

typedef short s16x8 __attribute__((ext_vector_type(8)));
typedef float f32x4 __attribute__((ext_vector_type(4)));
typedef __bf16 bf16_t;
typedef bf16_t bf16x4 __attribute__((ext_vector_type(4)));

#define MFMA16 __builtin_amdgcn_mfma_f32_16x16x32_bf16
#define C_DIM 128
#define S_DIM 1024

// ---------------------------------------------------------------------------
// K0: transpose W (32,128) -> Wt (128,32)
// ---------------------------------------------------------------------------
__global__ __launch_bounds__(256) void k_wt(const float* __restrict__ Ww,
                                            float* __restrict__ Wt) {
    for (int e = threadIdx.x; e < 32 * C_DIM; e += 256) {
        int d = e >> 7, c = e & (C_DIM - 1);
        Wt[c * 32 + d] = Ww[e];
    }
}

// ---------------------------------------------------------------------------
// K1 v2: LDS-staged projection + fused Vtb production.
//   Block = 256 tokens of one batch. Loop c in chunks of 16:
//   stage (x1+p1),(x2+p2) f32 tiles [16][256] via coalesced float4 loads;
//   x2 chunk also emits Vtb bf16 (channel-major) on the way through.
//   Then 16 rows x 32d FMA from LDS columns (2-way bank alias = free).
// ---------------------------------------------------------------------------
__global__ __launch_bounds__(256) void k_proj(
    const float* __restrict__ f1, const float* __restrict__ f2,
    const float* __restrict__ pos1, const float* __restrict__ pos2,
    const float* __restrict__ Wt, const float* __restrict__ Wb,
    bf16_t* __restrict__ fqb, bf16_t* __restrict__ fkb,
    bf16_t* __restrict__ Vtb) {
    __shared__ float LX1[16][260];
    __shared__ float LX2[16][260];
    const int tid = threadIdx.x;
    const int b = blockIdx.x >> 2;
    const int t0 = (blockIdx.x & 3) * 256;

    float q[32], k[32];
#pragma unroll
    for (int d = 0; d < 32; ++d) { q[d] = 0.f; k[d] = 0.f; }

    for (int cc = 0; cc < C_DIM; cc += 16) {
        __syncthreads();
        // stage: 16 rows x 256 cols = 1024 float4s, 4 per thread
#pragma unroll
        for (int it = 0; it < 4; ++it) {
            const int e4 = it * 256 + tid;
            const int r = e4 >> 6, t4 = (e4 & 63) << 2;
            const int c = cc + r;
            const size_t base = ((size_t)b * C_DIM + c) * S_DIM + t0 + t4;
            const float p1 = pos1[c], p2 = pos2[c];
            float4 v1 = *(const float4*)(f1 + base);
            float4 v2 = *(const float4*)(f2 + base);
            v1.x += p1; v1.y += p1; v1.z += p1; v1.w += p1;
            v2.x += p2; v2.y += p2; v2.z += p2; v2.w += p2;
            *(float4*)&LX1[r][t4] = v1;
            *(float4*)&LX2[r][t4] = v2;
            bf16x4 vb = {(bf16_t)v2.x, (bf16_t)v2.y, (bf16_t)v2.z, (bf16_t)v2.w};
            *(bf16x4*)(Vtb + base) = vb;   // Vtb layout == f2 layout
        }
        __syncthreads();
#pragma unroll 4
        for (int r = 0; r < 16; ++r) {
            const float a1 = LX1[r][tid];
            const float a2 = LX2[r][tid];
            const float* wrow = Wt + (cc + r) * 32;
#pragma unroll
            for (int d = 0; d < 32; ++d) {
                const float wv = wrow[d];
                q[d] = fmaf(wv, a1, q[d]);
                k[d] = fmaf(wv, a2, k[d]);
            }
        }
    }

    float sq = 0.f, sk = 0.f;
#pragma unroll
    for (int d = 0; d < 32; ++d) {
        q[d] += Wb[d]; k[d] += Wb[d];
        sq = fmaf(q[d], q[d], sq);
        sk = fmaf(k[d], k[d], sk);
    }
    const float rq = 30.0f / fmaxf(sqrtf(sq), 1e-12f);  // fold TEMP into q
    const float rk = 1.0f / fmaxf(sqrtf(sk), 1e-12f);
    const size_t g = (size_t)b * S_DIM + t0 + tid;
    bf16_t* oq = fqb + g * 32;
    bf16_t* ok = fkb + g * 32;
#pragma unroll
    for (int c4 = 0; c4 < 8; ++c4) {
        bf16x4 vq = {(bf16_t)(q[c4 * 4] * rq), (bf16_t)(q[c4 * 4 + 1] * rq),
                     (bf16_t)(q[c4 * 4 + 2] * rq), (bf16_t)(q[c4 * 4 + 3] * rq)};
        bf16x4 vk = {(bf16_t)(k[c4 * 4] * rk), (bf16_t)(k[c4 * 4 + 1] * rk),
                     (bf16_t)(k[c4 * 4 + 2] * rk), (bf16_t)(k[c4 * 4 + 3] * rk)};
        *(bf16x4*)(oq + c4 * 4) = vq;
        *(bf16x4*)(ok + c4 * 4) = vk;
    }
}

static __device__ __forceinline__ unsigned int pkbf(float a, float b) {
    union { bf16_t h[2]; unsigned int u; } z;
    z.h[0] = (bf16_t)a; z.h[1] = (bf16_t)b;
    return z.u;
}

// ---------------------------------------------------------------------------
// K2 v3: swapped-QK MFMA flash attention.
//   Block = (64 q, batch), 4 waves x 16 q. Grid 1024 -> 4 blocks/CU.
//   QK swapped: mfma(A=K, B=Q) -> D[k][q]: q = lane column -> per-lane
//   softmax scalars (m,l,corr), column reduce = 2 shfl_xor (16,32).
//   P -> PV B-frag: slot (Q,j) needs P[32h+8Q+j][q] living at lane
//   (l15, 2(Q&1)+(j>>2)), reg [2h+(Q>>1)][j&3]: 16 shfl + 8 cndmask/iter.
//   PV (swapped): D[c][q] = mfma(A=V, B=P) -> channel-major out.
//   T13 defer-rescale: skip acc*corr when __all(mx <= m+8).
//   LDS 23.6KB: Ks[64][40], Vs[128][72].
// ---------------------------------------------------------------------------
__global__ __launch_bounds__(256) void k_attn(
    const bf16_t* __restrict__ fqb, const bf16_t* __restrict__ fkb,
    const bf16_t* __restrict__ Vtb, float* __restrict__ fr,
    float* __restrict__ ssq) {
    __shared__ __align__(16) bf16_t Ks[64][40];
    __shared__ __align__(16) bf16_t Vs[128][72];
    __shared__ float wred[4];

    const int tid = threadIdx.x;
    const int w = tid >> 6;
    const int lane = tid & 63;
    const int l15 = lane & 15;
    const int Q = lane >> 4;
    const int b = blockIdx.y;
    const int qw = blockIdx.x * 64 + w * 16;

    // Q B-fragment: col=l15 (token qw+l15), d-slice Q*8..Q*8+7
    const s16x8 qa =
        *(const s16x8*)(fqb + ((size_t)b * S_DIM + qw + l15) * 32 + Q * 8);

    f32x4 acc[8];
    const f32x4 fz = {0.f, 0.f, 0.f, 0.f};
#pragma unroll
    for (int cg = 0; cg < 8; ++cg) acc[cg] = fz;
    float m = -1e30f, l = 0.f;
    const int srcbase = l15 + 32 * (Q & 1);  // exchange source quarter base
    const int nsel = Q >> 1;

    for (int kb = 0; kb < 16; ++kb) {
        const int k0 = kb * 64;
        __syncthreads();
        // stage K tile: Ks[key][d] (1 s16x8/thread)
        {
            const int row = tid >> 2, c8 = (tid & 3) * 8;
            *(s16x8*)&Ks[row][c8] =
                *(const s16x8*)(fkb + ((size_t)b * S_DIM + k0 + row) * 32 + c8);
        }
        // stage V tile: Vs[chan][key] (4 s16x8/thread)
#pragma unroll
        for (int it = 0; it < 4; ++it) {
            const int e = it * 256 + tid;
            const int row = e >> 3, c8 = (e & 7) * 8;
            *(s16x8*)&Vs[row][c8] =
                *(const s16x8*)(Vtb + ((size_t)b * C_DIM + row) * S_DIM + k0 + c8);
        }
        __syncthreads();

        // QK^T swapped: sc[n] rows = k-local 16n+4Q+s, col = q = l15
        f32x4 sc[4];
#pragma unroll
        for (int n = 0; n < 4; ++n) {
            const s16x8 kf = *(const s16x8*)&Ks[l15 + 16 * n][Q * 8];
            sc[n] = MFMA16(kf, qa, fz, 0, 0, 0);
        }

        // column softmax: per-lane max over 16 regs, then cross-quarter
        float mx = sc[0][0];
#pragma unroll
        for (int n = 0; n < 4; ++n)
#pragma unroll
            for (int s = 0; s < 4; ++s) mx = fmaxf(mx, sc[n][s]);
        mx = fmaxf(mx, __shfl_xor(mx, 16));
        mx = fmaxf(mx, __shfl_xor(mx, 32));

        if (!__all(mx <= m + 8.0f)) {       // T13 defer-rescale
            const float mn = fmaxf(m, mx);
            const float corr = __expf(m - mn);
#pragma unroll
            for (int cg = 0; cg < 8; ++cg) {
                acc[cg][0] *= corr; acc[cg][1] *= corr;
                acc[cg][2] *= corr; acc[cg][3] *= corr;
            }
            l *= corr; m = mn;
        }

        float pv[4][4];
        float sum = 0.f;
#pragma unroll
        for (int n = 0; n < 4; ++n)
#pragma unroll
            for (int s = 0; s < 4; ++s) {
                pv[n][s] = __expf(sc[n][s] - m);
                sum += pv[n][s];
            }
        sum += __shfl_xor(sum, 16);
        sum += __shfl_xor(sum, 32);
        l += sum;

        // pack P pairs (s0,s1),(s2,s3) per n
        unsigned int wpk[4][2];
#pragma unroll
        for (int n = 0; n < 4; ++n) {
            wpk[n][0] = pkbf(pv[n][0], pv[n][1]);
            wpk[n][1] = pkbf(pv[n][2], pv[n][3]);
        }

        // exchange + PV
#pragma unroll
        for (int h = 0; h < 2; ++h) {
            union { unsigned int u[4]; s16x8 v; } pb;
#pragma unroll
            for (int half = 0; half < 2; ++half)
#pragma unroll
                for (int a = 0; a < 2; ++a) {
                    const int src = srcbase + 16 * half;
                    const unsigned int g0 = __shfl((int)wpk[2 * h][a], src);
                    const unsigned int g1 = __shfl((int)wpk[2 * h + 1][a], src);
                    pb.u[half * 2 + a] = nsel ? g1 : g0;
                }
#pragma unroll
            for (int cg = 0; cg < 8; ++cg) {
                const s16x8 va = *(const s16x8*)&Vs[16 * cg + l15][h * 32 + Q * 8];
                acc[cg] = MFMA16(va, pb.v, acc[cg], 0, 0, 0);
            }
        }
    }

    const float invq = 1.0f / l;   // per-lane: col q = l15

    // epilogue: O/l + residual, channel-major write, ssq accumulate
    float sp = 0.f;
#pragma unroll
    for (int cg = 0; cg < 8; ++cg) {
#pragma unroll
        for (int s = 0; s < 4; ++s) {
            const int c = 16 * cg + 4 * Q + s;
            const size_t idx = ((size_t)b * C_DIM + c) * S_DIM + qw + l15;
            const float val = acc[cg][s] * invq + (float)Vtb[idx];
            fr[idx] = val;
            sp = fmaf(val, val, sp);
        }
    }
    sp += __shfl_down(sp, 32);
    sp += __shfl_down(sp, 16);
    sp += __shfl_down(sp, 8);
    sp += __shfl_down(sp, 4);
    sp += __shfl_down(sp, 2);
    sp += __shfl_down(sp, 1);
    if (lane == 0) wred[w] = sp;
    __syncthreads();
    if (tid == 0)
        atomicAdd(&ssq[b], wred[0] + wred[1] + wred[2] + wred[3]);
}

// ---------------------------------------------------------------------------
// K3: in-place instance-norm scale of d_out (fr already channel-major)
// ---------------------------------------------------------------------------
__global__ __launch_bounds__(256) void k_out(float* __restrict__ fr,
                                             const float* __restrict__ ssq) {
    const int b = blockIdx.x >> 5;
    const float scale =
        0.022097086912079608f * sqrtf(131072.0f / (ssq[b] + 1e-5f));
    float4* p = (float4*)fr + (size_t)blockIdx.x * 1024;
#pragma unroll
    for (int it = 0; it < 4; ++it) {
        float4 v = p[it * 256 + threadIdx.x];
        v.x *= scale; v.y *= scale; v.z *= scale; v.w *= scale;
        p[it * 256 + threadIdx.x] = v;
    }
}

// ---------------------------------------------------------------------------
extern "C" void kernel_launch(void* const* d_in, const int* in_sizes, int n_in,
                              void* d_out, int out_size, void* d_ws,
                              size_t ws_size, hipStream_t stream) {
    const float* f1 = (const float*)d_in[0];
    const float* f2 = (const float*)d_in[1];
    const float* pos1 = (const float*)d_in[2];
    const float* pos2 = (const float*)d_in[3];
    const float* Ww = (const float*)d_in[4];
    const float* Wb = (const float*)d_in[5];
    float* out = (float*)d_out;

    // ws layout (25.2 MB): fqb | fkb | Vtb | Wt | ssq
    bf16_t* fqb = (bf16_t*)d_ws;
    bf16_t* fkb = fqb + 2097152;
    bf16_t* Vtb = fkb + 2097152;                       // 8,388,608 bf16
    float* Wt = (float*)((char*)d_ws + 25165824);
    float* ssq = (float*)((char*)d_ws + 25182208);

    k_wt<<<1, 256, 0, stream>>>(Ww, Wt);
    k_proj<<<256, 256, 0, stream>>>(f1, f2, pos1, pos2, Wt, Wb, fqb, fkb, Vtb);
    hipMemsetAsync(ssq, 0, 256, stream);
    k_attn<<<dim3(16, 64), 256, 0, stream>>>(fqb, fkb, Vtb, out, ssq);
    k_out<<<2048, 256, 0, stream>>>(out, ssq);
}

// Round 7
// 214.878 us; speedup vs baseline: 2.3045x; 1.0291x over previous
//
#include <hip/hip_runtime.h>
#include <math.h>

typedef short s16x8 __attribute__((ext_vector_type(8)));
typedef float f32x4 __attribute__((ext_vector_type(4)));
typedef __bf16 bf16_t;
typedef bf16_t bf16x4 __attribute__((ext_vector_type(4)));
typedef bf16_t bf16x8 __attribute__((ext_vector_type(8)));

#define MFMA16 __builtin_amdgcn_mfma_f32_16x16x32_bf16
#define C_DIM 128
#define S_DIM 1024
#define LOG2E 1.44269504088896f

// ---------------------------------------------------------------------------
// K_v: Vtb[b][c][t] = bf16(f2[b][c][t] + pos2[c])   (channel-major, final V)
// ---------------------------------------------------------------------------
__global__ __launch_bounds__(256) void k_v(const float* __restrict__ f2,
                                           const float* __restrict__ pos2,
                                           bf16_t* __restrict__ Vtb) {
    const int i = blockIdx.x * 256 + threadIdx.x;        // float4 index
    float4 v = ((const float4*)f2)[i];
    const float p = pos2[(i >> 8) & (C_DIM - 1)];
    bf16x4 o = {(bf16_t)(v.x + p), (bf16_t)(v.y + p),
                (bf16_t)(v.z + p), (bf16_t)(v.w + p)};
    *(bf16x4*)(Vtb + (size_t)i * 4) = o;
}

// ---------------------------------------------------------------------------
// K1 v3: c-split projection. Block = 128 tokens (512 thr, 8 waves).
//   Thread (wave w, lane): token t = t0 + w*16 + (lane&15),
//   channels c in [Q*32, Q*32+32) where Q = lane>>4.
//   W staged in LDS quarter-interleaved LW[j][Q][d] (pad 36: 16B-aligned,
//   quarters land on disjoint bank groups). Butterfly shfl_xor(16/32)
//   combines the 4 quarter-partials; every lane then has full q[32],k[32],
//   computes the norm redundantly and writes its d-slice (bf16x8).
//   q scaled by 30*log2e (exp2 softmax downstream).
// ---------------------------------------------------------------------------
__global__ __launch_bounds__(512) void k_proj(
    const float* __restrict__ f1, const float* __restrict__ f2,
    const float* __restrict__ pos1, const float* __restrict__ pos2,
    const float* __restrict__ Ww, const float* __restrict__ Wb,
    bf16_t* __restrict__ fqb, bf16_t* __restrict__ fkb) {
    __shared__ float LW[32][4][36];   // 18.4 KB
    __shared__ float LP1[C_DIM], LP2[C_DIM];
    const int tid = threadIdx.x;
    const int w = tid >> 6;
    const int lane = tid & 63;
    const int l15 = lane & 15;
    const int Q = lane >> 4;
    const int b = blockIdx.x >> 3;
    const int t0 = (blockIdx.x & 7) * 128;

    // stage W (quarter-interleaved) + pos
#pragma unroll
    for (int it = 0; it < 8; ++it) {
        const int e = it * 512 + tid;
        const int d = e >> 7, c = e & 127;
        LW[c & 31][c >> 5][d] = Ww[e];
    }
    if (tid < C_DIM) { LP1[tid] = pos1[tid]; LP2[tid] = pos2[tid]; }
    __syncthreads();

    const int t = t0 + w * 16 + l15;
    const float* x1 = f1 + (size_t)b * C_DIM * S_DIM + t;
    const float* x2 = f2 + (size_t)b * C_DIM * S_DIM + t;

    float q[32], k[32];
#pragma unroll
    for (int d = 0; d < 32; ++d) { q[d] = 0.f; k[d] = 0.f; }

#pragma unroll 4
    for (int j = 0; j < 32; ++j) {
        const int c = Q * 32 + j;
        const float a1 = x1[(size_t)c * S_DIM] + LP1[c];
        const float a2 = x2[(size_t)c * S_DIM] + LP2[c];
        const float* wr = &LW[j][Q][0];
#pragma unroll
        for (int d = 0; d < 32; ++d) {
            const float wv = wr[d];
            q[d] = fmaf(wv, a1, q[d]);
            k[d] = fmaf(wv, a2, k[d]);
        }
    }

    // combine quarter-partials: butterfly over lane^16, lane^32
#pragma unroll
    for (int d = 0; d < 32; ++d) {
        q[d] += __shfl_xor(q[d], 16);
        q[d] += __shfl_xor(q[d], 32);
        k[d] += __shfl_xor(k[d], 16);
        k[d] += __shfl_xor(k[d], 32);
    }

    float sq = 0.f, sk = 0.f;
#pragma unroll
    for (int d = 0; d < 32; ++d) {
        q[d] += Wb[d]; k[d] += Wb[d];
        sq = fmaf(q[d], q[d], sq);
        sk = fmaf(k[d], k[d], sk);
    }
    const float rq = (30.0f * LOG2E) / fmaxf(sqrtf(sq), 1e-12f);  // TEMP+log2e
    const float rk = 1.0f / fmaxf(sqrtf(sk), 1e-12f);

    // write own d-slice [Q*8, Q*8+8)
    const size_t g = (size_t)b * S_DIM + t;
    bf16x8 vq, vk;
#pragma unroll
    for (int jj = 0; jj < 8; ++jj) {
        vq[jj] = (bf16_t)(q[Q * 8 + jj] * rq);
        vk[jj] = (bf16_t)(k[Q * 8 + jj] * rk);
    }
    *(bf16x8*)(fqb + g * 32 + Q * 8) = vq;
    *(bf16x8*)(fkb + g * 32 + Q * 8) = vk;
}

static __device__ __forceinline__ unsigned int pkbf(float a, float b) {
    union { bf16_t h[2]; unsigned int u; } z;
    z.h[0] = (bf16_t)a; z.h[1] = (bf16_t)b;
    return z.u;
}

// ---------------------------------------------------------------------------
// K2 v4: swapped-QK MFMA flash attention + XCD-aware block swizzle.
//   Grid 1024 1-D: xcd=l&7, slot=l>>3, b=(slot>>4)*8+xcd, qb=slot&15
//   -> all 16 q-blocks of a batch share one XCD's L2 (K/V panels resident).
//   QK swapped: mfma(A=K, B=Q) -> D[k][q]: per-lane softmax scalars.
//   P -> PV B-frag via 16 shfl + 8 selects (in-register).
//   PV swapped: D[c][q] = mfma(A=V, B=P) -> channel-major out.
//   exp2 softmax (log2e folded into q at projection); T13 thr 8*log2e.
//   LDS 23.6KB: Ks[64][40], Vs[128][72].
// ---------------------------------------------------------------------------
__global__ __launch_bounds__(256) void k_attn(
    const bf16_t* __restrict__ fqb, const bf16_t* __restrict__ fkb,
    const bf16_t* __restrict__ Vtb, float* __restrict__ fr,
    float* __restrict__ ssq) {
    __shared__ __align__(16) bf16_t Ks[64][40];
    __shared__ __align__(16) bf16_t Vs[128][72];
    __shared__ float wred[4];

    const int tid = threadIdx.x;
    const int w = tid >> 6;
    const int lane = tid & 63;
    const int l15 = lane & 15;
    const int Q = lane >> 4;

    // XCD swizzle (1024 = 8 XCD x 128, bijective)
    const int ell = blockIdx.x;
    const int xcd = ell & 7;
    const int slot = ell >> 3;
    const int b = (slot >> 4) * 8 + xcd;
    const int qb = slot & 15;
    const int qw = qb * 64 + w * 16;

    // Q B-fragment: col=l15 (token qw+l15), d-slice Q*8..Q*8+7
    const s16x8 qa =
        *(const s16x8*)(fqb + ((size_t)b * S_DIM + qw + l15) * 32 + Q * 8);

    f32x4 acc[8];
    const f32x4 fz = {0.f, 0.f, 0.f, 0.f};
#pragma unroll
    for (int cg = 0; cg < 8; ++cg) acc[cg] = fz;
    float m = -1e30f, l = 0.f;
    const int srcbase = l15 + 32 * (Q & 1);
    const int nsel = Q >> 1;

    for (int kb = 0; kb < 16; ++kb) {
        const int k0 = kb * 64;
        __syncthreads();
        {
            const int row = tid >> 2, c8 = (tid & 3) * 8;
            *(s16x8*)&Ks[row][c8] =
                *(const s16x8*)(fkb + ((size_t)b * S_DIM + k0 + row) * 32 + c8);
        }
#pragma unroll
        for (int it = 0; it < 4; ++it) {
            const int e = it * 256 + tid;
            const int row = e >> 3, c8 = (e & 7) * 8;
            *(s16x8*)&Vs[row][c8] =
                *(const s16x8*)(Vtb + ((size_t)b * C_DIM + row) * S_DIM + k0 + c8);
        }
        __syncthreads();

        // QK^T swapped: sc[n] rows = k-local 16n+4Q+s, col = q = l15
        f32x4 sc[4];
#pragma unroll
        for (int n = 0; n < 4; ++n) {
            const s16x8 kf = *(const s16x8*)&Ks[l15 + 16 * n][Q * 8];
            sc[n] = MFMA16(kf, qa, fz, 0, 0, 0);
        }

        // column softmax (logits already in log2 units)
        float mx = sc[0][0];
#pragma unroll
        for (int n = 0; n < 4; ++n)
#pragma unroll
            for (int s = 0; s < 4; ++s) mx = fmaxf(mx, sc[n][s]);
        mx = fmaxf(mx, __shfl_xor(mx, 16));
        mx = fmaxf(mx, __shfl_xor(mx, 32));

        if (!__all(mx <= m + 11.5416f)) {    // T13 defer-rescale (8*log2e)
            const float mn = fmaxf(m, mx);
            const float corr = exp2f(m - mn);
#pragma unroll
            for (int cg = 0; cg < 8; ++cg) {
                acc[cg][0] *= corr; acc[cg][1] *= corr;
                acc[cg][2] *= corr; acc[cg][3] *= corr;
            }
            l *= corr; m = mn;
        }

        float pv[4][4];
        float sum = 0.f;
#pragma unroll
        for (int n = 0; n < 4; ++n)
#pragma unroll
            for (int s = 0; s < 4; ++s) {
                pv[n][s] = exp2f(sc[n][s] - m);
                sum += pv[n][s];
            }
        sum += __shfl_xor(sum, 16);
        sum += __shfl_xor(sum, 32);
        l += sum;

        unsigned int wpk[4][2];
#pragma unroll
        for (int n = 0; n < 4; ++n) {
            wpk[n][0] = pkbf(pv[n][0], pv[n][1]);
            wpk[n][1] = pkbf(pv[n][2], pv[n][3]);
        }

        // exchange + PV
#pragma unroll
        for (int h = 0; h < 2; ++h) {
            union { unsigned int u[4]; s16x8 v; } pb;
#pragma unroll
            for (int half = 0; half < 2; ++half)
#pragma unroll
                for (int a = 0; a < 2; ++a) {
                    const int src = srcbase + 16 * half;
                    const unsigned int g0 = __shfl((int)wpk[2 * h][a], src);
                    const unsigned int g1 = __shfl((int)wpk[2 * h + 1][a], src);
                    pb.u[half * 2 + a] = nsel ? g1 : g0;
                }
#pragma unroll
            for (int cg = 0; cg < 8; ++cg) {
                const s16x8 va = *(const s16x8*)&Vs[16 * cg + l15][h * 32 + Q * 8];
                acc[cg] = MFMA16(va, pb.v, acc[cg], 0, 0, 0);
            }
        }
    }

    const float invq = 1.0f / l;

    float sp = 0.f;
#pragma unroll
    for (int cg = 0; cg < 8; ++cg) {
#pragma unroll
        for (int s = 0; s < 4; ++s) {
            const int c = 16 * cg + 4 * Q + s;
            const size_t idx = ((size_t)b * C_DIM + c) * S_DIM + qw + l15;
            const float val = acc[cg][s] * invq + (float)Vtb[idx];
            fr[idx] = val;
            sp = fmaf(val, val, sp);
        }
    }
    sp += __shfl_down(sp, 32);
    sp += __shfl_down(sp, 16);
    sp += __shfl_down(sp, 8);
    sp += __shfl_down(sp, 4);
    sp += __shfl_down(sp, 2);
    sp += __shfl_down(sp, 1);
    if (lane == 0) wred[w] = sp;
    __syncthreads();
    if (tid == 0)
        atomicAdd(&ssq[b], wred[0] + wred[1] + wred[2] + wred[3]);
}

// ---------------------------------------------------------------------------
// K3: in-place instance-norm scale of d_out (fr already channel-major)
// ---------------------------------------------------------------------------
__global__ __launch_bounds__(256) void k_out(float* __restrict__ fr,
                                             const float* __restrict__ ssq) {
    const int b = blockIdx.x >> 5;
    const float scale =
        0.022097086912079608f * sqrtf(131072.0f / (ssq[b] + 1e-5f));
    float4* p = (float4*)fr + (size_t)blockIdx.x * 1024;
#pragma unroll
    for (int it = 0; it < 4; ++it) {
        float4 v = p[it * 256 + threadIdx.x];
        v.x *= scale; v.y *= scale; v.z *= scale; v.w *= scale;
        p[it * 256 + threadIdx.x] = v;
    }
}

// ---------------------------------------------------------------------------
extern "C" void kernel_launch(void* const* d_in, const int* in_sizes, int n_in,
                              void* d_out, int out_size, void* d_ws,
                              size_t ws_size, hipStream_t stream) {
    const float* f1 = (const float*)d_in[0];
    const float* f2 = (const float*)d_in[1];
    const float* pos1 = (const float*)d_in[2];
    const float* pos2 = (const float*)d_in[3];
    const float* Ww = (const float*)d_in[4];
    const float* Wb = (const float*)d_in[5];
    float* out = (float*)d_out;

    // ws layout (25.2 MB): fqb | fkb | Vtb | ssq
    bf16_t* fqb = (bf16_t*)d_ws;
    bf16_t* fkb = fqb + 2097152;
    bf16_t* Vtb = fkb + 2097152;                       // 8,388,608 bf16
    float* ssq = (float*)((char*)d_ws + 25165824);

    k_proj<<<512, 512, 0, stream>>>(f1, f2, pos1, pos2, Ww, Wb, fqb, fkb);
    k_v<<<8192, 256, 0, stream>>>(f2, pos2, Vtb);
    hipMemsetAsync(ssq, 0, 256, stream);
    k_attn<<<1024, 256, 0, stream>>>(fqb, fkb, Vtb, out, ssq);
    k_out<<<2048, 256, 0, stream>>>(out, ssq);
}